// Round 1
// baseline (262.149 us; speedup 1.0000x reference)
//
#include <hip/hip_runtime.h>

// Problem constants: x is (256, 3, 224, 224) float32.
#define N_IMG   256
#define HW      (224 * 224)        // 50176
#define CHW     (3 * HW)           // 150528 floats per image
#define V4      (CHW / 4)          // 37632 float4 per image
#define THREADS 256

// mean_kernel partition: 7 parts * (21 float4/thread * 256 threads) = 37632
#define PARTS       7
#define PART_V4     (V4 / PARTS)       // 5376
#define PER_THREAD  (PART_V4 / THREADS) // 21

// apply_kernel partition: 147 chunks * 256 threads * 1 float4 = 37632
#define CHUNKS  (V4 / THREADS)     // 147

#define MAGS_PER_TF 9

__device__ __forceinline__ float clip01(float v) {
    return fminf(fmaxf(v, 0.0f), 1.0f);
}

// Kernel 1: per-image mean partials — only for images that actually need it
// (tf_idx == 1 (contrast) AND apply_mask[sample] > 0). Others early-exit;
// their partial slots stay poisoned but are never read downstream.
__global__ __launch_bounds__(THREADS) void mean_kernel(
        const float* __restrict__ x,
        const int* __restrict__ sample,
        const int* __restrict__ apply_mask,
        float* __restrict__ partials /* [N_IMG][PARTS] */) {
    const int img  = blockIdx.y;
    const int part = blockIdx.x;
    const int s    = sample[img];
    const int tf   = s / MAGS_PER_TF;
    if (tf != 1 || apply_mask[s] <= 0) return;

    const float4* xp = (const float4*)x + (size_t)img * V4 + (size_t)part * PART_V4;
    float sum = 0.0f;
#pragma unroll
    for (int k = 0; k < PER_THREAD; ++k) {
        float4 v = xp[threadIdx.x + k * THREADS];
        sum += (v.x + v.y) + (v.z + v.w);
    }
    // wave (64-lane) shuffle reduction
#pragma unroll
    for (int off = 32; off > 0; off >>= 1)
        sum += __shfl_down(sum, off, 64);

    __shared__ float wsum[THREADS / 64];
    if ((threadIdx.x & 63) == 0) wsum[threadIdx.x >> 6] = sum;
    __syncthreads();
    if (threadIdx.x == 0) {
        float t = (wsum[0] + wsum[1]) + (wsum[2] + wsum[3]);
        partials[img * PARTS + part] = t;
    }
}

// Kernel 2: elementwise transform, one float4 per thread, wave-uniform branch
// per image (the whole block works on one image).
__global__ __launch_bounds__(THREADS) void apply_kernel(
        const float* __restrict__ x,
        const int* __restrict__ sample,
        const int* __restrict__ apply_mask,
        const float* __restrict__ partials,
        float* __restrict__ out) {
    const int img   = blockIdx.y;
    const int chunk = blockIdx.x;
    const int s     = sample[img];
    const int tf    = s / MAGS_PER_TF;
    const float mag = (float)(s % MAGS_PER_TF + 1) / 10.0f;
    const bool applied = apply_mask[s] > 0;

    const size_t idx = (size_t)img * V4 + (size_t)chunk * THREADS + threadIdx.x;
    const float4* xp = (const float4*)x;
    float4*       op = (float4*)out;

    float4 v = xp[idx];
    float4 r;

    if (!applied) {
        r = v;
    } else if (tf == 0) {            // brightness: clip(x + mag)
        r.x = clip01(v.x + mag);
        r.y = clip01(v.y + mag);
        r.z = clip01(v.z + mag);
        r.w = clip01(v.w + mag);
    } else if (tf == 1) {            // contrast: clip(mean + (x-mean)*(1+mag))
        float mean = 0.0f;
#pragma unroll
        for (int p = 0; p < PARTS; ++p) mean += partials[img * PARTS + p];
        mean /= (float)CHW;
        const float g = 1.0f + mag;
        r.x = clip01(mean + (v.x - mean) * g);
        r.y = clip01(mean + (v.y - mean) * g);
        r.z = clip01(mean + (v.z - mean) * g);
        r.w = clip01(mean + (v.w - mean) * g);
    } else if (tf == 2) {            // invert-lerp: (1-mag)*x + mag*(1-x)  (NO clip)
        const float a = 1.0f - mag;
        r.x = a * v.x + mag * (1.0f - v.x);
        r.y = a * v.y + mag * (1.0f - v.y);
        r.z = a * v.z + mag * (1.0f - v.z);
        r.w = a * v.w + mag * (1.0f - v.w);
    } else {                         // gain: clip(x * (1+mag))
        const float g = 1.0f + mag;
        r.x = clip01(v.x * g);
        r.y = clip01(v.y * g);
        r.z = clip01(v.z * g);
        r.w = clip01(v.w * g);
    }
    op[idx] = r;
}

extern "C" void kernel_launch(void* const* d_in, const int* in_sizes, int n_in,
                              void* d_out, int out_size, void* d_ws, size_t ws_size,
                              hipStream_t stream) {
    const float* x          = (const float*)d_in[0];
    const int*   sample     = (const int*)d_in[1];
    const int*   apply_mask = (const int*)d_in[2];
    float*       out        = (float*)d_out;
    float*       partials   = (float*)d_ws;   // N_IMG * PARTS floats = 7 KiB

    dim3 mgrid(PARTS, N_IMG);
    mean_kernel<<<mgrid, THREADS, 0, stream>>>(x, sample, apply_mask, partials);

    dim3 agrid(CHUNKS, N_IMG);
    apply_kernel<<<agrid, THREADS, 0, stream>>>(x, sample, apply_mask, partials, out);
}